// Round 1
// baseline (535.233 us; speedup 1.0000x reference)
//
#include <hip/hip_runtime.h>
#include <stdint.h>
#include <stddef.h>

// AttentionGCNLayer: B=4, N=2048, D=256, E=3 edge types, H=2 heads, I=2 GCN iters.
// Outputs: out (4,2048,256) fp32 then graph_attention (2,4,2048,2048) fp32.
// Workspace budget used: ~140 MB.

typedef unsigned short bf16_t;
typedef __attribute__((ext_vector_type(4))) float floatx4;
typedef __attribute__((ext_vector_type(8))) __bf16 bf16x8;
typedef __attribute__((ext_vector_type(4))) unsigned short u16x4;

#define NEGV -1000000000.0f

__device__ __forceinline__ bf16_t f2b(float f) {
  union { float f; uint32_t u; } v; v.f = f;
  uint32_t r = v.u + 0x7FFFu + ((v.u >> 16) & 1u);   // round-to-nearest-even
  return (bf16_t)(r >> 16);
}

typedef __attribute__((address_space(1))) void gvoid_t;
typedef __attribute__((address_space(3))) void svoid_t;
__device__ __forceinline__ void gll16(const void* g, void* l) {
  __builtin_amdgcn_global_load_lds((gvoid_t*)(g), (svoid_t*)(l), 16, 0, 0);
}

// ---------------------------------------------------------------------------
// m97-style BT-GEMM core: C[128x128] tile, BK=32, 256 threads = 4 waves (2x2),
// each wave 64x64 via 4x4 MFMA 16x16x32 bf16 tiles. A[m][k] row-major,
// B passed as BT[n][k] row-major. Requires lda/ldb multiples of 8, K mult 32.
// ---------------------------------------------------------------------------
__device__ __forceinline__ void gemm_core(
    const bf16_t* __restrict__ A, int lda, int rowA0,
    const bf16_t* __restrict__ Bt, int ldb, int rowB0,
    int K, bf16_t* lA, bf16_t* lB, floatx4 acc[4][4])
{
  const int lane = threadIdx.x & 63;
  const int wave = threadIdx.x >> 6;
  const int l16  = lane & 15;
  const int quad = lane >> 4;
  const int wm = (wave >> 1) << 6;
  const int wn = (wave & 1) << 6;
  const int srow = (wave << 5) + (lane >> 2);    // staging row (this lane)
  const int scol = (lane & 3) << 3;              // staging col (8 bf16 = 16 B)
  const bf16_t* gA0 = A + (size_t)(rowA0 + srow) * lda + scol;
  const bf16_t* gA1 = gA0 + (size_t)16 * lda;
  const bf16_t* gB0 = Bt + (size_t)(rowB0 + srow) * ldb + scol;
  const bf16_t* gB1 = gB0 + (size_t)16 * ldb;
  bf16_t* lA0 = lA + (wave << 5) * 32;           // wave-uniform LDS dst
  bf16_t* lA1 = lA0 + 16 * 32;
  bf16_t* lB0 = lB + (wave << 5) * 32;
  bf16_t* lB1 = lB0 + 16 * 32;

  for (int k0 = 0; k0 < K; k0 += 32) {
    __syncthreads();                             // prev ds_reads done
    gll16(gA0 + k0, lA0);
    gll16(gA1 + k0, lA1);
    gll16(gB0 + k0, lB0);
    gll16(gB1 + k0, lB1);
    __syncthreads();                             // drains vmcnt before barrier
    bf16x8 af[4], bv[4];
#pragma unroll
    for (int mi = 0; mi < 4; ++mi)
      af[mi] = *(const bf16x8*)(lA + ((wm + mi * 16 + l16) << 5) + (quad << 3));
#pragma unroll
    for (int ni = 0; ni < 4; ++ni)
      bv[ni] = *(const bf16x8*)(lB + ((wn + ni * 16 + l16) << 5) + (quad << 3));
#pragma unroll
    for (int mi = 0; mi < 4; ++mi)
#pragma unroll
      for (int ni = 0; ni < 4; ++ni)
        acc[mi][ni] = __builtin_amdgcn_mfma_f32_16x16x32_bf16(af[mi], bv[ni], acc[mi][ni], 0, 0, 0);
  }
}

#define TILE_IDS \
  const int lane = threadIdx.x & 63; \
  const int wave = threadIdx.x >> 6; \
  const int l16  = lane & 15; \
  const int quad = lane >> 4; \
  const int wm = (wave >> 1) << 6; \
  const int wn = (wave & 1) << 6;

#define ZERO4(acc) \
  { const floatx4 z4_ = {0.f, 0.f, 0.f, 0.f}; \
    for (int mi_ = 0; mi_ < 4; ++mi_) for (int ni_ = 0; ni_ < 4; ++ni_) acc[mi_][ni_] = z4_; }

// --------------------------------------------------------------------------
__global__ __launch_bounds__(256) void k_cast_x(const float* __restrict__ x,
                                                bf16_t* __restrict__ xb) {
  int i = blockIdx.x * 256 + threadIdx.x;        // 262144 groups of 8
  float4 a = ((const float4*)x)[i * 2];
  float4 b = ((const float4*)x)[i * 2 + 1];
  bf16_t o[8] = { f2b(a.x), f2b(a.y), f2b(a.z), f2b(a.w),
                  f2b(b.x), f2b(b.y), f2b(b.z), f2b(b.w) };
  ((uint4*)xb)[i] = *(uint4*)o;
}

// Transposed bf16 weight casts: WqkT[z][n][k]=W[k][n], gWT[i][f][k], aWT[f][k]
__global__ __launch_bounds__(256) void k_cast_w(
    const float* __restrict__ Wq, const float* __restrict__ Wk,
    const float* __restrict__ gW, const float* __restrict__ aW,
    bf16_t* __restrict__ WqkT, bf16_t* __restrict__ gWT, bf16_t* __restrict__ aWT) {
  int idx = blockIdx.x * 256 + threadIdx.x;
  if (idx < 393216) {                            // 6 * 65536
    int zz = idx >> 16, r = idx & 65535;
    int n = r >> 8, k = r & 255;
    const float* src = (zz < 3) ? (Wq + (size_t)zz * 65536) : (Wk + (size_t)(zz - 3) * 65536);
    WqkT[idx] = f2b(src[k * 256 + n]);
  } else if (idx < 524288) {                     // + 2 * 65536
    int t = idx - 393216;
    int i = t >> 16, r = t & 65535;
    int f = r >> 8, k = r & 255;
    gWT[t] = f2b(gW[(size_t)i * 65536 + k * 256 + f]);
  } else if (idx < 655360) {                     // + 131072
    int t = idx - 524288;
    int f = t >> 9, k = t & 511;
    aWT[t] = f2b(aW[k * 256 + f]);
  }
}

// Q/K projections: z in [0,6) = {Wq0..2, Wk0..2}. Writes concatenated-K layout
// qcat/kcat[b][h][n][e*128 + kk], kk = col&127, h = col>>7.
__global__ __launch_bounds__(256) void k_gemm_proj(
    const bf16_t* __restrict__ xb, const bf16_t* __restrict__ WqkT,
    const float* __restrict__ bq, const float* __restrict__ bk,
    bf16_t* __restrict__ qcat, bf16_t* __restrict__ kcat) {
  __shared__ bf16_t lA[4096], lB[4096];
  int z = blockIdx.z;
  int e = (z < 3) ? z : z - 3;
  const bf16_t* Wz = WqkT + (size_t)z * 65536;
  const float* bias = ((z < 3) ? bq : bk) + e * 256;
  bf16_t* dst = (z < 3) ? qcat : kcat;
  int bm0 = blockIdx.y * 128, bn0 = blockIdx.x * 128;
  floatx4 acc[4][4];
  ZERO4(acc);
  gemm_core(xb, 256, bm0, Wz, 256, bn0, 256, lA, lB, acc);
  TILE_IDS;
#pragma unroll
  for (int mi = 0; mi < 4; ++mi)
#pragma unroll
    for (int ni = 0; ni < 4; ++ni)
#pragma unroll
      for (int r = 0; r < 4; ++r) {
        int row = bm0 + wm + mi * 16 + quad * 4 + r;   // b*2048+n
        int col = bn0 + wn + ni * 16 + l16;            // h*128+kk
        int b = row >> 11, n = row & 2047;
        int h = col >> 7, kk = col & 127;
        float v = acc[mi][ni][r] + bias[col];
        dst[((size_t)((b * 2 + h) * 2048 + n)) * 384 + e * 128 + kk] = f2b(v);
      }
}

// Masked scores: per (h,b) tile, K=384 processed as 3 chunks of 128;
// select raw where adj==e+1, NEG where adj==0. Writes fp32 to d_out graph
// region, layout [h][b][n][m] (z = h*4+b).
__global__ __launch_bounds__(256) void k_scores(
    const bf16_t* __restrict__ qcat, const bf16_t* __restrict__ kcat,
    const int* __restrict__ adj, float* __restrict__ sc) {
  __shared__ bf16_t lA[4096], lB[4096];
  int z = blockIdx.z;
  int h = z >> 2, b = z & 3;
  const bf16_t* A  = qcat + (size_t)(b * 2 + h) * 2048 * 384;
  const bf16_t* Bt = kcat + (size_t)(b * 2 + h) * 2048 * 384;
  const int* adjb = adj + (size_t)b * 2048 * 2048;
  int bm0 = blockIdx.y * 128, bn0 = blockIdx.x * 128;
  TILE_IDS;

  uint32_t adjv[4][4];
#pragma unroll
  for (int mi = 0; mi < 4; ++mi)
#pragma unroll
    for (int ni = 0; ni < 4; ++ni) {
      int col = bn0 + wn + ni * 16 + l16;
      uint32_t v = 0;
#pragma unroll
      for (int r = 0; r < 4; ++r) {
        int row = bm0 + wm + mi * 16 + quad * 4 + r;
        v |= ((uint32_t)adjb[(size_t)row * 2048 + col] & 3u) << (r * 8);
      }
      adjv[mi][ni] = v;
    }

  floatx4 sel[4][4];
  ZERO4(sel);
  for (int e = 0; e < 3; ++e) {
    floatx4 acc[4][4];
    ZERO4(acc);
    gemm_core(A + e * 128, 384, bm0, Bt + e * 128, 384, bn0, 128, lA, lB, acc);
#pragma unroll
    for (int mi = 0; mi < 4; ++mi)
#pragma unroll
      for (int ni = 0; ni < 4; ++ni) {
        uint32_t av = adjv[mi][ni];
#pragma unroll
        for (int r = 0; r < 4; ++r) {
          bool m = (((av >> (r * 8)) & 255u) == (uint32_t)(e + 1));
          sel[mi][ni][r] = m ? acc[mi][ni][r] : sel[mi][ni][r];
        }
      }
  }
  const float scale = 0.08838834764831845f;      // 1/sqrt(dk=128)
#pragma unroll
  for (int mi = 0; mi < 4; ++mi)
#pragma unroll
    for (int ni = 0; ni < 4; ++ni)
#pragma unroll
      for (int r = 0; r < 4; ++r) {
        int row = bm0 + wm + mi * 16 + quad * 4 + r;
        int col = bn0 + wn + ni * 16 + l16;
        uint32_t a = (adjv[mi][ni] >> (r * 8)) & 255u;
        float v = (a == 0u) ? NEGV : sel[mi][ni][r] * scale;
        sc[((size_t)z * 2048 + row) * 2048 + col] = v;
      }
}

// Row softmax, wave per row; fp32 in-place + bf16 copy (degs==1 by construction).
__global__ __launch_bounds__(256) void k_softmax(float* __restrict__ sc,
                                                 bf16_t* __restrict__ abf) {
  int row = blockIdx.x * 4 + (threadIdx.x >> 6);
  int lane = threadIdx.x & 63;
  float4* p4 = (float4*)(sc + (size_t)row * 2048);
  float4 v[8];
  float mx = -3.4e38f;
#pragma unroll
  for (int j = 0; j < 8; ++j) {
    v[j] = p4[j * 64 + lane];
    mx = fmaxf(mx, fmaxf(fmaxf(v[j].x, v[j].y), fmaxf(v[j].z, v[j].w)));
  }
#pragma unroll
  for (int off = 32; off; off >>= 1) mx = fmaxf(mx, __shfl_xor(mx, off));
  float s = 0.f;
#pragma unroll
  for (int j = 0; j < 8; ++j) {
    v[j].x = __expf(v[j].x - mx); v[j].y = __expf(v[j].y - mx);
    v[j].z = __expf(v[j].z - mx); v[j].w = __expf(v[j].w - mx);
    s += v[j].x + v[j].y + v[j].z + v[j].w;
  }
#pragma unroll
  for (int off = 32; off; off >>= 1) s += __shfl_xor(s, off);
  float inv = 1.0f / s;
  u16x4* b4 = (u16x4*)(abf + (size_t)row * 2048);
#pragma unroll
  for (int j = 0; j < 8; ++j) {
    float4 o;
    o.x = v[j].x * inv; o.y = v[j].y * inv; o.z = v[j].z * inv; o.w = v[j].w * inv;
    p4[j * 64 + lane] = o;
    u16x4 ov = { f2b(o.x), f2b(o.y), f2b(o.z), f2b(o.w) };
    b4[j * 64 + lane] = ov;
  }
}

// Plain GEMM, bf16 out [m][256]: used for h1 = x @ gcn_W[i] (W pre-transposed).
__global__ __launch_bounds__(256) void k_gemm_bf16(
    const bf16_t* __restrict__ A, const bf16_t* __restrict__ Wt,
    bf16_t* __restrict__ C) {
  __shared__ bf16_t lA[4096], lB[4096];
  int bm0 = blockIdx.y * 128, bn0 = blockIdx.x * 128;
  floatx4 acc[4][4];
  ZERO4(acc);
  gemm_core(A, 256, bm0, Wt, 256, bn0, 256, lA, lB, acc);
  TILE_IDS;
#pragma unroll
  for (int mi = 0; mi < 4; ++mi)
#pragma unroll
    for (int ni = 0; ni < 4; ++ni)
#pragma unroll
      for (int r = 0; r < 4; ++r) {
        int row = bm0 + wm + mi * 16 + quad * 4 + r;
        int col = bn0 + wn + ni * 16 + l16;
        C[(size_t)row * 256 + col] = f2b(acc[mi][ni][r]);
      }
}

// 64x64 bf16 tile transpose: in [z][rows][cols] -> out [z][cols][rows].
__global__ __launch_bounds__(256) void k_transpose(
    const bf16_t* __restrict__ in, bf16_t* __restrict__ out, int rows, int cols) {
  __shared__ bf16_t t[64][72];                   // 144 B rows (16-aligned)
  size_t zoff = (size_t)blockIdx.z * rows * cols;
  in += zoff; out += zoff;
  int r0 = blockIdx.y * 64, c0 = blockIdx.x * 64;
  int tid = threadIdx.x;
  for (int u = tid; u < 512; u += 256) {
    int rr = u >> 3, cc = (u & 7) * 8;
    uint4 v = *(const uint4*)&in[(size_t)(r0 + rr) * cols + c0 + cc];
    *(uint4*)&t[rr][cc] = v;
  }
  __syncthreads();
  for (int u = tid; u < 512; u += 256) {
    int rr = u >> 3, cc = (u & 7) * 8;
    bf16_t tmp[8];
#pragma unroll
    for (int i = 0; i < 8; ++i) tmp[i] = t[cc + i][rr];
    *(uint4*)&out[(size_t)(c0 + rr) * rows + r0 + cc] = *(uint4*)tmp;
  }
}

// sum_nei = attn @ h1 with epilogue x_new = x_old + relu(acc + gcn_b).
// z = h*4+b. B operand is h1T (pre-transposed, BT layout [f][m]).
__global__ __launch_bounds__(256) void k_spmm(
    const bf16_t* __restrict__ abf, const bf16_t* __restrict__ h1T,
    long sBb, long sBh, const float* __restrict__ bias,
    const float* __restrict__ rin, long rib, long rih,
    float* __restrict__ rout,
    bf16_t* __restrict__ obf, long obb, long obh, int ldo) {
  __shared__ bf16_t lA[4096], lB[4096];
  int z = blockIdx.z, h = z >> 2, b = z & 3;
  const bf16_t* A  = abf + (size_t)z * 2048 * 2048;
  const bf16_t* Bt = h1T + (size_t)b * sBb + (size_t)h * sBh;
  const float* rz  = rin + (size_t)b * rib + (size_t)h * rih;
  bf16_t* oz = obf + (size_t)b * obb + (size_t)h * obh;
  int bm0 = blockIdx.y * 128, bn0 = blockIdx.x * 128;
  floatx4 acc[4][4];
  ZERO4(acc);
  gemm_core(A, 2048, bm0, Bt, 2048, bn0, 2048, lA, lB, acc);
  TILE_IDS;
#pragma unroll
  for (int mi = 0; mi < 4; ++mi)
#pragma unroll
    for (int ni = 0; ni < 4; ++ni)
#pragma unroll
      for (int r = 0; r < 4; ++r) {
        int row = bm0 + wm + mi * 16 + quad * 4 + r;
        int col = bn0 + wn + ni * 16 + l16;
        float s = acc[mi][ni][r] + bias[col];
        float xn = rz[(size_t)row * 256 + col] + fmaxf(s, 0.f);
        if (rout) rout[((size_t)z * 2048 + row) * 256 + col] = xn;
        oz[(size_t)row * ldo + col] = f2b(xn);
      }
}

// Final: out = xcat(8192x512) @ aggW(512x256) + agg_b, fp32.
__global__ __launch_bounds__(256) void k_final(
    const bf16_t* __restrict__ xcat, const bf16_t* __restrict__ aWT,
    const float* __restrict__ ab, float* __restrict__ out) {
  __shared__ bf16_t lA[4096], lB[4096];
  int bm0 = blockIdx.y * 128, bn0 = blockIdx.x * 128;
  floatx4 acc[4][4];
  ZERO4(acc);
  gemm_core(xcat, 512, bm0, aWT, 512, bn0, 512, lA, lB, acc);
  TILE_IDS;
#pragma unroll
  for (int mi = 0; mi < 4; ++mi)
#pragma unroll
    for (int ni = 0; ni < 4; ++ni)
#pragma unroll
      for (int r = 0; r < 4; ++r) {
        int row = bm0 + wm + mi * 16 + quad * 4 + r;
        int col = bn0 + wn + ni * 16 + l16;
        out[(size_t)row * 256 + col] = acc[mi][ni][r] + ab[col];
      }
}

// ---------------------------------------------------------------------------
extern "C" void kernel_launch(void* const* d_in, const int* in_sizes, int n_in,
                              void* d_out, int out_size, void* d_ws, size_t ws_size,
                              hipStream_t stream) {
  const float* x   = (const float*)d_in[0];
  const int*   adj = (const int*)d_in[1];
  const float* Wq  = (const float*)d_in[2];
  const float* bq  = (const float*)d_in[3];
  const float* Wk  = (const float*)d_in[4];
  const float* bk  = (const float*)d_in[5];
  const float* gW  = (const float*)d_in[6];
  const float* gb  = (const float*)d_in[7];
  const float* aW  = (const float*)d_in[8];
  const float* ab  = (const float*)d_in[9];
  float* out = (float*)d_out;                    // (4,2048,256)
  float* sc  = out + 2097152;                    // graph_attention (2,4,2048,2048)

  char* w = (char*)d_ws;
  bf16_t* xb   = (bf16_t*)w; w += 4194304;       // 8192x256 bf16
  bf16_t* WqkT = (bf16_t*)w; w += 786432;        // 6x256x256
  bf16_t* gWT  = (bf16_t*)w; w += 262144;        // 2x256x256
  bf16_t* aWT  = (bf16_t*)w; w += 262144;        // 256x512
  bf16_t* qcat = (bf16_t*)w; w += 12582912;      // [b][h][2048][384]
  bf16_t* kcat = (bf16_t*)w; w += 12582912;
  bf16_t* abf  = (bf16_t*)w; w += 67108864;      // [h][b][2048][2048] bf16
  bf16_t* h1a  = (bf16_t*)w; w += 4194304;       // [b][2048][256]
  bf16_t* h1T  = (bf16_t*)w; w += 4194304;       // [b][256][2048]
  float*  x1   = (float*)w;  w += 16777216;      // [h][b][2048][256] fp32
  bf16_t* x1b  = (bf16_t*)w; w += 8388608;       // [h][b][2048][256] bf16
  bf16_t* h1b  = (bf16_t*)w; w += 8388608;       // [h][b][2048][256] bf16
  bf16_t* h1T1 = qcat;                           // alias (free after k_scores)
  bf16_t* xcat = kcat;                           // alias (free after k_scores)

  k_cast_x<<<1024, 256, 0, stream>>>(x, xb);
  k_cast_w<<<2560, 256, 0, stream>>>(Wq, Wk, gW, aW, WqkT, gWT, aWT);
  k_gemm_proj<<<dim3(2, 64, 6), 256, 0, stream>>>(xb, WqkT, bq, bk, qcat, kcat);
  k_scores<<<dim3(16, 16, 8), 256, 0, stream>>>(qcat, kcat, adj, sc);
  k_softmax<<<4096, 256, 0, stream>>>(sc, abf);
  // GCN iter 0 (h1 shared across heads since x0 identical)
  k_gemm_bf16<<<dim3(2, 64, 1), 256, 0, stream>>>(xb, gWT, h1a);
  k_transpose<<<dim3(4, 32, 4), 256, 0, stream>>>(h1a, h1T, 2048, 256);
  k_spmm<<<dim3(2, 16, 8), 256, 0, stream>>>(abf, h1T, 524288L, 0L, gb,
                                             x, 524288L, 0L, x1,
                                             x1b, 524288L, 2097152L, 256);
  // GCN iter 1 (per-head x)
  k_gemm_bf16<<<dim3(2, 128, 1), 256, 0, stream>>>(x1b, gWT + 65536, h1b);
  k_transpose<<<dim3(4, 32, 8), 256, 0, stream>>>(h1b, h1T1, 2048, 256);
  k_spmm<<<dim3(2, 16, 8), 256, 0, stream>>>(abf, h1T1, 524288L, 2097152L, gb + 256,
                                             x1, 524288L, 2097152L, nullptr,
                                             xcat, 1048576L, 256L, 512);
  // Final aggregation
  k_final<<<dim3(2, 64, 1), 256, 0, stream>>>(xcat, aWT, ab, out);
}

// Round 2
// 513.079 us; speedup vs baseline: 1.0432x; 1.0432x over previous
//
#include <hip/hip_runtime.h>
#include <stdint.h>
#include <stddef.h>

// AttentionGCNLayer: B=4, N=2048, D=256, E=3 edge types, H=2 heads, I=2 GCN iters.
// Outputs: out (4,2048,256) fp32 then graph_attention (2,4,2048,2048) fp32.
// R2: 64x128 tile cores for scores/spmm (occupancy), LDS k-chunk XOR swizzle
// (8-way -> 2-way bank conflicts), transpose fused into GCN GEMM epilogue.

typedef unsigned short bf16_t;
typedef __attribute__((ext_vector_type(4))) float floatx4;
typedef __attribute__((ext_vector_type(8))) __bf16 bf16x8;
typedef __attribute__((ext_vector_type(4))) unsigned short u16x4;

#define NEGV -1000000000.0f

__device__ __forceinline__ bf16_t f2b(float f) {
  union { float f; uint32_t u; } v; v.f = f;
  uint32_t r = v.u + 0x7FFFu + ((v.u >> 16) & 1u);   // round-to-nearest-even
  return (bf16_t)(r >> 16);
}

typedef __attribute__((address_space(1))) void gvoid_t;
typedef __attribute__((address_space(3))) void svoid_t;
__device__ __forceinline__ void gll16(const void* g, void* l) {
  __builtin_amdgcn_global_load_lds((gvoid_t*)(g), (svoid_t*)(l), 16, 0, 0);
}

// Swizzled LDS fragment read: physical k-chunk = (logical_quad + row/2) & 3.
// Spreads the 16 lanes of a quarter across all 8 4-bank groups (2-way = free).
__device__ __forceinline__ bf16x8 lds_frag(const bf16_t* base, int row, int quad) {
  return *(const bf16x8*)(base + (row << 5) + (((quad + (row >> 1)) & 3) << 3));
}

// ---------------------------------------------------------------------------
// 128x128 BT-GEMM core (m97-style): BK=32, 256 thr = 4 waves (2x2), wave 64x64.
// A[m][k] row-major, B as BT[n][k] row-major. lda/ldb mult of 8, K mult 32.
// ---------------------------------------------------------------------------
__device__ __forceinline__ void gemm_core(
    const bf16_t* __restrict__ A, int lda, int rowA0,
    const bf16_t* __restrict__ Bt, int ldb, int rowB0,
    int K, bf16_t* lA, bf16_t* lB, floatx4 acc[4][4])
{
  const int lane = threadIdx.x & 63;
  const int wave = threadIdx.x >> 6;
  const int l16  = lane & 15;
  const int quad = lane >> 4;
  const int wm = (wave >> 1) << 6;
  const int wn = (wave & 1) << 6;
  const int srow = (wave << 5) + (lane >> 2);          // staging row
  const int scol = (((lane & 3) - (srow >> 1)) & 3) << 3;  // swizzled logical col
  const bf16_t* gA0 = A + (size_t)(rowA0 + srow) * lda + scol;
  const bf16_t* gA1 = gA0 + (size_t)16 * lda;          // (srow+16)>>1 ≡ srow>>1 mod 4
  const bf16_t* gB0 = Bt + (size_t)(rowB0 + srow) * ldb + scol;
  const bf16_t* gB1 = gB0 + (size_t)16 * ldb;
  bf16_t* lA0 = lA + (wave << 5) * 32;                 // wave-uniform LDS dst
  bf16_t* lA1 = lA0 + 16 * 32;
  bf16_t* lB0 = lB + (wave << 5) * 32;
  bf16_t* lB1 = lB0 + 16 * 32;

  for (int k0 = 0; k0 < K; k0 += 32) {
    __syncthreads();
    gll16(gA0 + k0, lA0);
    gll16(gA1 + k0, lA1);
    gll16(gB0 + k0, lB0);
    gll16(gB1 + k0, lB1);
    __syncthreads();
    bf16x8 af[4], bv[4];
#pragma unroll
    for (int mi = 0; mi < 4; ++mi) af[mi] = lds_frag(lA, wm + mi * 16 + l16, quad);
#pragma unroll
    for (int ni = 0; ni < 4; ++ni) bv[ni] = lds_frag(lB, wn + ni * 16 + l16, quad);
#pragma unroll
    for (int mi = 0; mi < 4; ++mi)
#pragma unroll
      for (int ni = 0; ni < 4; ++ni)
        acc[mi][ni] = __builtin_amdgcn_mfma_f32_16x16x32_bf16(af[mi], bv[ni], acc[mi][ni], 0, 0, 0);
  }
}

// ---------------------------------------------------------------------------
// 64x128 BT-GEMM core: all 4 waves share the 64 A-rows; wave covers 32 cols
// (wn = wave*32, 4x2 MFMA tiles). Halves accumulator VGPRs vs 128x128.
// lA = 2048 bf16 (4 KB), lB = 4096 bf16 (8 KB).
// ---------------------------------------------------------------------------
__device__ __forceinline__ void gemm_core64(
    const bf16_t* __restrict__ A, int lda, int rowA0,
    const bf16_t* __restrict__ Bt, int ldb, int rowB0,
    int K, bf16_t* lA, bf16_t* lB, floatx4 acc[4][2])
{
  const int lane = threadIdx.x & 63;
  const int wave = threadIdx.x >> 6;
  const int l16  = lane & 15;
  const int quad = lane >> 4;
  const int wn   = wave << 5;
  const int tr   = (wave << 4) + (lane >> 2);          // 0..63
  const int scol = (((lane & 3) - (tr >> 1)) & 3) << 3;
  const bf16_t* gA  = A  + (size_t)(rowA0 + tr) * lda + scol;
  const bf16_t* gB0 = Bt + (size_t)(rowB0 + tr) * ldb + scol;
  const bf16_t* gB1 = gB0 + (size_t)64 * ldb;          // rows 64..127, same swizzle
  bf16_t* lAd = lA + (wave << 9);                      // wave*1024 B
  bf16_t* lB0 = lB + (wave << 9);
  bf16_t* lB1 = lB + 2048 + (wave << 9);

  for (int k0 = 0; k0 < K; k0 += 32) {
    __syncthreads();
    gll16(gA  + k0, lAd);
    gll16(gB0 + k0, lB0);
    gll16(gB1 + k0, lB1);
    __syncthreads();
    bf16x8 af[4], bv[2];
#pragma unroll
    for (int mi = 0; mi < 4; ++mi) af[mi] = lds_frag(lA, mi * 16 + l16, quad);
#pragma unroll
    for (int ni = 0; ni < 2; ++ni) bv[ni] = lds_frag(lB, wn + ni * 16 + l16, quad);
#pragma unroll
    for (int mi = 0; mi < 4; ++mi)
#pragma unroll
      for (int ni = 0; ni < 2; ++ni)
        acc[mi][ni] = __builtin_amdgcn_mfma_f32_16x16x32_bf16(af[mi], bv[ni], acc[mi][ni], 0, 0, 0);
  }
}

#define TILE_IDS \
  const int lane = threadIdx.x & 63; \
  const int wave = threadIdx.x >> 6; \
  const int l16  = lane & 15; \
  const int quad = lane >> 4; \
  const int wm = (wave >> 1) << 6; \
  const int wn = (wave & 1) << 6;

#define TILE_IDS64 \
  const int lane = threadIdx.x & 63; \
  const int wave = threadIdx.x >> 6; \
  const int l16  = lane & 15; \
  const int quad = lane >> 4; \
  const int wn = wave << 5;

#define ZERO44(acc) \
  { const floatx4 z4_ = {0.f, 0.f, 0.f, 0.f}; \
    for (int mi_ = 0; mi_ < 4; ++mi_) for (int ni_ = 0; ni_ < 4; ++ni_) acc[mi_][ni_] = z4_; }
#define ZERO42(acc) \
  { const floatx4 z4_ = {0.f, 0.f, 0.f, 0.f}; \
    for (int mi_ = 0; mi_ < 4; ++mi_) for (int ni_ = 0; ni_ < 2; ++ni_) acc[mi_][ni_] = z4_; }

// --------------------------------------------------------------------------
__global__ __launch_bounds__(256) void k_cast_x(const float* __restrict__ x,
                                                bf16_t* __restrict__ xb) {
  int i = blockIdx.x * 256 + threadIdx.x;
  float4 a = ((const float4*)x)[i * 2];
  float4 b = ((const float4*)x)[i * 2 + 1];
  bf16_t o[8] = { f2b(a.x), f2b(a.y), f2b(a.z), f2b(a.w),
                  f2b(b.x), f2b(b.y), f2b(b.z), f2b(b.w) };
  ((uint4*)xb)[i] = *(uint4*)o;
}

__global__ __launch_bounds__(256) void k_cast_w(
    const float* __restrict__ Wq, const float* __restrict__ Wk,
    const float* __restrict__ gW, const float* __restrict__ aW,
    bf16_t* __restrict__ WqkT, bf16_t* __restrict__ gWT, bf16_t* __restrict__ aWT) {
  int idx = blockIdx.x * 256 + threadIdx.x;
  if (idx < 393216) {                            // 6 * 65536
    int zz = idx >> 16, r = idx & 65535;
    int n = r >> 8, k = r & 255;
    const float* src = (zz < 3) ? (Wq + (size_t)zz * 65536) : (Wk + (size_t)(zz - 3) * 65536);
    WqkT[idx] = f2b(src[k * 256 + n]);
  } else if (idx < 524288) {                     // + 2 * 65536
    int t = idx - 393216;
    int i = t >> 16, r = t & 65535;
    int f = r >> 8, k = r & 255;
    gWT[t] = f2b(gW[(size_t)i * 65536 + k * 256 + f]);
  } else if (idx < 655360) {                     // + 131072
    int t = idx - 524288;
    int f = t >> 9, k = t & 511;
    aWT[t] = f2b(aW[k * 256 + f]);
  }
}

// Q/K projections -> concatenated-K layout qcat/kcat[b][h][n][e*128+kk].
__global__ __launch_bounds__(256) void k_gemm_proj(
    const bf16_t* __restrict__ xb, const bf16_t* __restrict__ WqkT,
    const float* __restrict__ bq, const float* __restrict__ bk,
    bf16_t* __restrict__ qcat, bf16_t* __restrict__ kcat) {
  __shared__ bf16_t lA[4096], lB[4096];
  int z = blockIdx.z;
  int e = (z < 3) ? z : z - 3;
  const bf16_t* Wz = WqkT + (size_t)z * 65536;
  const float* bias = ((z < 3) ? bq : bk) + e * 256;
  bf16_t* dst = (z < 3) ? qcat : kcat;
  int bm0 = blockIdx.y * 128, bn0 = blockIdx.x * 128;
  floatx4 acc[4][4];
  ZERO44(acc);
  gemm_core(xb, 256, bm0, Wz, 256, bn0, 256, lA, lB, acc);
  TILE_IDS;
#pragma unroll
  for (int mi = 0; mi < 4; ++mi)
#pragma unroll
    for (int ni = 0; ni < 4; ++ni)
#pragma unroll
      for (int r = 0; r < 4; ++r) {
        int row = bm0 + wm + mi * 16 + quad * 4 + r;   // b*2048+n
        int col = bn0 + wn + ni * 16 + l16;            // h*128+kk
        int b = row >> 11, n = row & 2047;
        int h = col >> 7, kk = col & 127;
        float v = acc[mi][ni][r] + bias[col];
        dst[((size_t)((b * 2 + h) * 2048 + n)) * 384 + e * 128 + kk] = f2b(v);
      }
}

// Masked scores, 64x128 tile. z = h*4+b, writes fp32 [h][b][n][m].
__global__ __launch_bounds__(256) void k_scores(
    const bf16_t* __restrict__ qcat, const bf16_t* __restrict__ kcat,
    const int* __restrict__ adj, float* __restrict__ sc) {
  __shared__ bf16_t lA[2048], lB[4096];
  int z = blockIdx.z;
  int h = z >> 2, b = z & 3;
  const bf16_t* A  = qcat + (size_t)(b * 2 + h) * 2048 * 384;
  const bf16_t* Bt = kcat + (size_t)(b * 2 + h) * 2048 * 384;
  const int* adjb = adj + (size_t)b * 2048 * 2048;
  int bm0 = blockIdx.y * 64, bn0 = blockIdx.x * 128;
  TILE_IDS64;

  uint32_t adjv[4][2];
#pragma unroll
  for (int mi = 0; mi < 4; ++mi)
#pragma unroll
    for (int ni = 0; ni < 2; ++ni) {
      int col = bn0 + wn + ni * 16 + l16;
      uint32_t v = 0;
#pragma unroll
      for (int r = 0; r < 4; ++r) {
        int row = bm0 + mi * 16 + quad * 4 + r;
        v |= ((uint32_t)adjb[(size_t)row * 2048 + col] & 3u) << (r * 8);
      }
      adjv[mi][ni] = v;
    }

  floatx4 sel[4][2];
  ZERO42(sel);
  for (int e = 0; e < 3; ++e) {
    floatx4 acc[4][2];
    ZERO42(acc);
    gemm_core64(A + e * 128, 384, bm0, Bt + e * 128, 384, bn0, 128, lA, lB, acc);
#pragma unroll
    for (int mi = 0; mi < 4; ++mi)
#pragma unroll
      for (int ni = 0; ni < 2; ++ni) {
        uint32_t av = adjv[mi][ni];
#pragma unroll
        for (int r = 0; r < 4; ++r) {
          bool m = (((av >> (r * 8)) & 255u) == (uint32_t)(e + 1));
          sel[mi][ni][r] = m ? acc[mi][ni][r] : sel[mi][ni][r];
        }
      }
  }
  const float scale = 0.08838834764831845f;      // 1/sqrt(dk=128)
#pragma unroll
  for (int mi = 0; mi < 4; ++mi)
#pragma unroll
    for (int ni = 0; ni < 2; ++ni)
#pragma unroll
      for (int r = 0; r < 4; ++r) {
        int row = bm0 + mi * 16 + quad * 4 + r;
        int col = bn0 + wn + ni * 16 + l16;
        uint32_t a = (adjv[mi][ni] >> (r * 8)) & 255u;
        float v = (a == 0u) ? NEGV : sel[mi][ni][r] * scale;
        sc[((size_t)z * 2048 + row) * 2048 + col] = v;
      }
}

// Row softmax, wave per row; fp32 in-place + bf16 copy (degs==1 by construction).
__global__ __launch_bounds__(256) void k_softmax(float* __restrict__ sc,
                                                 bf16_t* __restrict__ abf) {
  int row = blockIdx.x * 4 + (threadIdx.x >> 6);
  int lane = threadIdx.x & 63;
  float4* p4 = (float4*)(sc + (size_t)row * 2048);
  float4 v[8];
  float mx = -3.4e38f;
#pragma unroll
  for (int j = 0; j < 8; ++j) {
    v[j] = p4[j * 64 + lane];
    mx = fmaxf(mx, fmaxf(fmaxf(v[j].x, v[j].y), fmaxf(v[j].z, v[j].w)));
  }
#pragma unroll
  for (int off = 32; off; off >>= 1) mx = fmaxf(mx, __shfl_xor(mx, off));
  float s = 0.f;
#pragma unroll
  for (int j = 0; j < 8; ++j) {
    v[j].x = __expf(v[j].x - mx); v[j].y = __expf(v[j].y - mx);
    v[j].z = __expf(v[j].z - mx); v[j].w = __expf(v[j].w - mx);
    s += v[j].x + v[j].y + v[j].z + v[j].w;
  }
#pragma unroll
  for (int off = 32; off; off >>= 1) s += __shfl_xor(s, off);
  float inv = 1.0f / s;
  u16x4* b4 = (u16x4*)(abf + (size_t)row * 2048);
#pragma unroll
  for (int j = 0; j < 8; ++j) {
    float4 o;
    o.x = v[j].x * inv; o.y = v[j].y * inv; o.z = v[j].z * inv; o.w = v[j].w * inv;
    p4[j * 64 + lane] = o;
    u16x4 ov = { f2b(o.x), f2b(o.y), f2b(o.z), f2b(o.w) };
    b4[j * 64 + lane] = ov;
  }
}

// h1 = A @ Wt with TRANSPOSED bf16 write: CT[slice][256][2048], slice = row>>11.
// C-layout gives each lane 4 consecutive M-rows at one col -> one 8-B store.
__global__ __launch_bounds__(256) void k_gemm_bf16T(
    const bf16_t* __restrict__ A, const bf16_t* __restrict__ Wt,
    bf16_t* __restrict__ CT) {
  __shared__ bf16_t lA[4096], lB[4096];
  int bm0 = blockIdx.y * 128, bn0 = blockIdx.x * 128;
  floatx4 acc[4][4];
  ZERO44(acc);
  gemm_core(A, 256, bm0, Wt, 256, bn0, 256, lA, lB, acc);
  TILE_IDS;
#pragma unroll
  for (int mi = 0; mi < 4; ++mi)
#pragma unroll
    for (int ni = 0; ni < 4; ++ni) {
      int row0 = bm0 + wm + mi * 16 + quad * 4;        // 4 consecutive M rows
      int col  = bn0 + wn + ni * 16 + l16;
      int s = row0 >> 11, n = row0 & 2047;
      u16x4 v = { f2b(acc[mi][ni][0]), f2b(acc[mi][ni][1]),
                  f2b(acc[mi][ni][2]), f2b(acc[mi][ni][3]) };
      *(u16x4*)&CT[(size_t)s * 524288 + (size_t)col * 2048 + n] = v;
    }
}

// sum_nei = attn @ h1, 64x128 tile, epilogue x_new = x_old + relu(acc + gcn_b).
__global__ __launch_bounds__(256) void k_spmm(
    const bf16_t* __restrict__ abf, const bf16_t* __restrict__ h1T,
    long sBb, long sBh, const float* __restrict__ bias,
    const float* __restrict__ rin, long rib, long rih,
    float* __restrict__ rout,
    bf16_t* __restrict__ obf, long obb, long obh, int ldo) {
  __shared__ bf16_t lA[2048], lB[4096];
  int z = blockIdx.z, h = z >> 2, b = z & 3;
  const bf16_t* A  = abf + (size_t)z * 2048 * 2048;
  const bf16_t* Bt = h1T + (size_t)b * sBb + (size_t)h * sBh;
  const float* rz  = rin + (size_t)b * rib + (size_t)h * rih;
  bf16_t* oz = obf + (size_t)b * obb + (size_t)h * obh;
  int bm0 = blockIdx.y * 64, bn0 = blockIdx.x * 128;
  floatx4 acc[4][2];
  ZERO42(acc);
  gemm_core64(A, 2048, bm0, Bt, 2048, bn0, 2048, lA, lB, acc);
  TILE_IDS64;
#pragma unroll
  for (int mi = 0; mi < 4; ++mi)
#pragma unroll
    for (int ni = 0; ni < 2; ++ni)
#pragma unroll
      for (int r = 0; r < 4; ++r) {
        int row = bm0 + mi * 16 + quad * 4 + r;
        int col = bn0 + wn + ni * 16 + l16;
        float s = acc[mi][ni][r] + bias[col];
        float xn = rz[(size_t)row * 256 + col] + fmaxf(s, 0.f);
        if (rout) rout[((size_t)z * 2048 + row) * 256 + col] = xn;
        oz[(size_t)row * ldo + col] = f2b(xn);
      }
}

// Final: out = xcat(8192x512) @ aggW(512x256) + agg_b, fp32.
__global__ __launch_bounds__(256) void k_final(
    const bf16_t* __restrict__ xcat, const bf16_t* __restrict__ aWT,
    const float* __restrict__ ab, float* __restrict__ out) {
  __shared__ bf16_t lA[4096], lB[4096];
  int bm0 = blockIdx.y * 128, bn0 = blockIdx.x * 128;
  floatx4 acc[4][4];
  ZERO44(acc);
  gemm_core(xcat, 512, bm0, aWT, 512, bn0, 512, lA, lB, acc);
  TILE_IDS;
#pragma unroll
  for (int mi = 0; mi < 4; ++mi)
#pragma unroll
    for (int ni = 0; ni < 4; ++ni)
#pragma unroll
      for (int r = 0; r < 4; ++r) {
        int row = bm0 + wm + mi * 16 + quad * 4 + r;
        int col = bn0 + wn + ni * 16 + l16;
        out[(size_t)row * 256 + col] = acc[mi][ni][r] + ab[col];
      }
}

// ---------------------------------------------------------------------------
extern "C" void kernel_launch(void* const* d_in, const int* in_sizes, int n_in,
                              void* d_out, int out_size, void* d_ws, size_t ws_size,
                              hipStream_t stream) {
  const float* x   = (const float*)d_in[0];
  const int*   adj = (const int*)d_in[1];
  const float* Wq  = (const float*)d_in[2];
  const float* bq  = (const float*)d_in[3];
  const float* Wk  = (const float*)d_in[4];
  const float* bk  = (const float*)d_in[5];
  const float* gW  = (const float*)d_in[6];
  const float* gb  = (const float*)d_in[7];
  const float* aW  = (const float*)d_in[8];
  const float* ab  = (const float*)d_in[9];
  float* out = (float*)d_out;                    // (4,2048,256)
  float* sc  = out + 2097152;                    // graph_attention (2,4,2048,2048)

  char* w = (char*)d_ws;
  bf16_t* xb   = (bf16_t*)w; w += 4194304;       // 8192x256 bf16
  bf16_t* WqkT = (bf16_t*)w; w += 786432;        // 6x256x256
  bf16_t* gWT  = (bf16_t*)w; w += 262144;        // 2x256x256
  bf16_t* aWT  = (bf16_t*)w; w += 262144;        // 256x512
  bf16_t* qcat = (bf16_t*)w; w += 12582912;      // [b][h][2048][384]
  bf16_t* kcat = (bf16_t*)w; w += 12582912;
  bf16_t* abf  = (bf16_t*)w; w += 67108864;      // [h][b][2048][2048] bf16
  bf16_t* h1T  = (bf16_t*)w; w += 4194304;       // [b][256][2048]
  float*  x1   = (float*)w;  w += 16777216;      // [h][b][2048][256] fp32
  bf16_t* x1b  = (bf16_t*)w; w += 8388608;       // [h][b][2048][256] bf16
  bf16_t* h1T1 = qcat;                           // alias (free after k_scores)
  bf16_t* xcat = kcat;                           // alias (free after k_scores)

  k_cast_x<<<1024, 256, 0, stream>>>(x, xb);
  k_cast_w<<<2560, 256, 0, stream>>>(Wq, Wk, gW, aW, WqkT, gWT, aWT);
  k_gemm_proj<<<dim3(2, 64, 6), 256, 0, stream>>>(xb, WqkT, bq, bk, qcat, kcat);
  k_scores<<<dim3(16, 32, 8), 256, 0, stream>>>(qcat, kcat, adj, sc);
  k_softmax<<<4096, 256, 0, stream>>>(sc, abf);
  // GCN iter 0 (h1 shared across heads since x0 identical); transposed write
  k_gemm_bf16T<<<dim3(2, 64, 1), 256, 0, stream>>>(xb, gWT, h1T);
  k_spmm<<<dim3(2, 32, 8), 256, 0, stream>>>(abf, h1T, 524288L, 0L, gb,
                                             x, 524288L, 0L, x1,
                                             x1b, 524288L, 2097152L, 256);
  // GCN iter 1 (per-head x)
  k_gemm_bf16T<<<dim3(2, 128, 1), 256, 0, stream>>>(x1b, gWT + 65536, h1T1);
  k_spmm<<<dim3(2, 32, 8), 256, 0, stream>>>(abf, h1T1, 524288L, 2097152L, gb + 256,
                                             x1, 524288L, 2097152L, nullptr,
                                             xcat, 1048576L, 256L, 512);
  // Final aggregation
  k_final<<<dim3(2, 64, 1), 256, 0, stream>>>(xcat, aWT, ab, out);
}

// Round 3
// 415.930 us; speedup vs baseline: 1.2868x; 1.2336x over previous
//
#include <hip/hip_runtime.h>
#include <stdint.h>
#include <stddef.h>

// AttentionGCNLayer: B=4, N=2048, D=256, E=3 edge types, H=2 heads, I=2 GCN iters.
// Outputs: out (4,2048,256) fp32 then graph_attention (2,4,2048,2048) fp32.
// R3: k_scores BK=128 (3 barrier rounds, XOR-swizzled LDS), fp16 scores aliased
// into abf (saves 200+ MB traffic), z->XCD swizzle for L2 locality, spmm BK=64.

typedef unsigned short bf16_t;
typedef __attribute__((ext_vector_type(4))) float floatx4;
typedef __attribute__((ext_vector_type(8))) __bf16 bf16x8;
typedef __attribute__((ext_vector_type(4))) unsigned short u16x4;

__device__ __forceinline__ bf16_t f2b(float f) {
  union { float f; uint32_t u; } v; v.f = f;
  uint32_t r = v.u + 0x7FFFu + ((v.u >> 16) & 1u);   // round-to-nearest-even
  return (bf16_t)(r >> 16);
}
__device__ __forceinline__ float h2f(uint16_t u) {
  union { uint16_t u; _Float16 h; } v; v.u = u; return (float)v.h;
}
__device__ __forceinline__ uint16_t f2h(float f) {
  union { uint16_t u; _Float16 h; } v; v.h = (_Float16)f; return v.u;
}

typedef __attribute__((address_space(1))) void gvoid_t;
typedef __attribute__((address_space(3))) void svoid_t;
__device__ __forceinline__ void gll16(const void* g, void* l) {
  __builtin_amdgcn_global_load_lds((gvoid_t*)(g), (svoid_t*)(l), 16, 0, 0);
}

// ===== XOR-swizzled wide-BK staging & fragment reads ========================
// BK=128: row = 128 bf16 = 16 chunks of 8. phys_chunk = log_chunk ^ (row&15).
// BK=64:  row = 64 bf16  =  8 chunks of 8. phys_chunk = log_chunk ^ (row&7).
// Reads land 2-way per bank group (free, m136). Staging covers each row's full
// span (permuted within the row) so global coalescing is unaffected.

template <int NR>  // NR rows x 128 cols; wave w stages rows [w*NR/4, (w+1)*NR/4)
__device__ __forceinline__ void stage128(const bf16_t* G, int ldg, bf16_t* L) {
  const int lane = threadIdx.x & 63, wave = threadIdx.x >> 6;
  const int li = lane >> 4, cp = lane & 15;
#pragma unroll
  for (int t = 0; t < NR / 16; ++t) {
    int base_r = wave * (NR / 4) + t * 4;        // wave-uniform
    int r = base_r + li;
    int cl = cp ^ (r & 15);
    gll16(G + (size_t)r * ldg + cl * 8, L + base_r * 128);
  }
}
template <int NR>  // NR rows x 64 cols
__device__ __forceinline__ void stage64(const bf16_t* G, int ldg, bf16_t* L) {
  const int lane = threadIdx.x & 63, wave = threadIdx.x >> 6;
  const int li = lane >> 3, cp = lane & 7;
#pragma unroll
  for (int t = 0; t < NR / 32; ++t) {
    int base_r = wave * (NR / 4) + t * 8;        // wave-uniform
    int r = base_r + li;
    int cl = cp ^ (r & 7);
    gll16(G + (size_t)r * ldg + cl * 8, L + base_r * 64);
  }
}
__device__ __forceinline__ bf16x8 frag128(const bf16_t* L, int row, int j, int quad) {
  int c = ((j << 2) + quad) ^ (row & 15);
  return *(const bf16x8*)(L + (row << 7) + (c << 3));
}
__device__ __forceinline__ bf16x8 frag64(const bf16_t* L, int row, int j, int quad) {
  int c = ((j << 2) + quad) ^ (row & 7);
  return *(const bf16x8*)(L + (row << 6) + (c << 3));
}

// ===== R2 128x128 core (kept for proj / bf16T / final; verified) ============
__device__ __forceinline__ bf16x8 lds_frag(const bf16_t* base, int row, int quad) {
  return *(const bf16x8*)(base + (row << 5) + (((quad + (row >> 1)) & 3) << 3));
}
__device__ __forceinline__ void gemm_core(
    const bf16_t* __restrict__ A, int lda, int rowA0,
    const bf16_t* __restrict__ Bt, int ldb, int rowB0,
    int K, bf16_t* lA, bf16_t* lB, floatx4 acc[4][4])
{
  const int lane = threadIdx.x & 63;
  const int wave = threadIdx.x >> 6;
  const int l16  = lane & 15;
  const int quad = lane >> 4;
  const int wm = (wave >> 1) << 6;
  const int wn = (wave & 1) << 6;
  const int srow = (wave << 5) + (lane >> 2);
  const int scol = (((lane & 3) - (srow >> 1)) & 3) << 3;
  const bf16_t* gA0 = A + (size_t)(rowA0 + srow) * lda + scol;
  const bf16_t* gA1 = gA0 + (size_t)16 * lda;
  const bf16_t* gB0 = Bt + (size_t)(rowB0 + srow) * ldb + scol;
  const bf16_t* gB1 = gB0 + (size_t)16 * ldb;
  bf16_t* lA0 = lA + (wave << 5) * 32;
  bf16_t* lA1 = lA0 + 16 * 32;
  bf16_t* lB0 = lB + (wave << 5) * 32;
  bf16_t* lB1 = lB0 + 16 * 32;

  for (int k0 = 0; k0 < K; k0 += 32) {
    __syncthreads();
    gll16(gA0 + k0, lA0);
    gll16(gA1 + k0, lA1);
    gll16(gB0 + k0, lB0);
    gll16(gB1 + k0, lB1);
    __syncthreads();
    bf16x8 af[4], bv[4];
#pragma unroll
    for (int mi = 0; mi < 4; ++mi) af[mi] = lds_frag(lA, wm + mi * 16 + l16, quad);
#pragma unroll
    for (int ni = 0; ni < 4; ++ni) bv[ni] = lds_frag(lB, wn + ni * 16 + l16, quad);
#pragma unroll
    for (int mi = 0; mi < 4; ++mi)
#pragma unroll
      for (int ni = 0; ni < 4; ++ni)
        acc[mi][ni] = __builtin_amdgcn_mfma_f32_16x16x32_bf16(af[mi], bv[ni], acc[mi][ni], 0, 0, 0);
  }
}

#define TILE_IDS \
  const int lane = threadIdx.x & 63; \
  const int wave = threadIdx.x >> 6; \
  const int l16  = lane & 15; \
  const int quad = lane >> 4; \
  const int wm = (wave >> 1) << 6; \
  const int wn = (wave & 1) << 6;

#define TILE_IDS64 \
  const int lane = threadIdx.x & 63; \
  const int wave = threadIdx.x >> 6; \
  const int l16  = lane & 15; \
  const int quad = lane >> 4; \
  const int wn = wave << 5;

#define ZERO44(acc) \
  { const floatx4 z4_ = {0.f, 0.f, 0.f, 0.f}; \
    for (int mi_ = 0; mi_ < 4; ++mi_) for (int ni_ = 0; ni_ < 4; ++ni_) acc[mi_][ni_] = z4_; }
#define ZERO42(acc) \
  { const floatx4 z4_ = {0.f, 0.f, 0.f, 0.f}; \
    for (int mi_ = 0; mi_ < 4; ++mi_) for (int ni_ = 0; ni_ < 2; ++ni_) acc[mi_][ni_] = z4_; }

// --------------------------------------------------------------------------
__global__ __launch_bounds__(256) void k_cast_x(const float* __restrict__ x,
                                                bf16_t* __restrict__ xb) {
  int i = blockIdx.x * 256 + threadIdx.x;
  float4 a = ((const float4*)x)[i * 2];
  float4 b = ((const float4*)x)[i * 2 + 1];
  bf16_t o[8] = { f2b(a.x), f2b(a.y), f2b(a.z), f2b(a.w),
                  f2b(b.x), f2b(b.y), f2b(b.z), f2b(b.w) };
  ((uint4*)xb)[i] = *(uint4*)o;
}

__global__ __launch_bounds__(256) void k_cast_w(
    const float* __restrict__ Wq, const float* __restrict__ Wk,
    const float* __restrict__ gW, const float* __restrict__ aW,
    bf16_t* __restrict__ WqkT, bf16_t* __restrict__ gWT, bf16_t* __restrict__ aWT) {
  int idx = blockIdx.x * 256 + threadIdx.x;
  if (idx < 393216) {                            // 6 * 65536
    int zz = idx >> 16, r = idx & 65535;
    int n = r >> 8, k = r & 255;
    const float* src = (zz < 3) ? (Wq + (size_t)zz * 65536) : (Wk + (size_t)(zz - 3) * 65536);
    WqkT[idx] = f2b(src[k * 256 + n]);
  } else if (idx < 524288) {                     // + 2 * 65536
    int t = idx - 393216;
    int i = t >> 16, r = t & 65535;
    int f = r >> 8, k = r & 255;
    gWT[t] = f2b(gW[(size_t)i * 65536 + k * 256 + f]);
  } else if (idx < 655360) {                     // + 131072
    int t = idx - 524288;
    int f = t >> 9, k = t & 511;
    aWT[t] = f2b(aW[k * 256 + f]);
  }
}

// Q/K projections -> concatenated-K layout qcat/kcat[b][h][n][e*128+kk].
__global__ __launch_bounds__(256) void k_gemm_proj(
    const bf16_t* __restrict__ xb, const bf16_t* __restrict__ WqkT,
    const float* __restrict__ bq, const float* __restrict__ bk,
    bf16_t* __restrict__ qcat, bf16_t* __restrict__ kcat) {
  __shared__ bf16_t lA[4096], lB[4096];
  int z = blockIdx.z;
  int e = (z < 3) ? z : z - 3;
  const bf16_t* Wz = WqkT + (size_t)z * 65536;
  const float* bias = ((z < 3) ? bq : bk) + e * 256;
  bf16_t* dst = (z < 3) ? qcat : kcat;
  int bm0 = blockIdx.y * 128, bn0 = blockIdx.x * 128;
  floatx4 acc[4][4];
  ZERO44(acc);
  gemm_core(xb, 256, bm0, Wz, 256, bn0, 256, lA, lB, acc);
  TILE_IDS;
#pragma unroll
  for (int mi = 0; mi < 4; ++mi)
#pragma unroll
    for (int ni = 0; ni < 4; ++ni)
#pragma unroll
      for (int r = 0; r < 4; ++r) {
        int row = bm0 + wm + mi * 16 + quad * 4 + r;   // b*2048+n
        int col = bn0 + wn + ni * 16 + l16;            // h*128+kk
        int b = row >> 11, n = row & 2047;
        int h = col >> 7, kk = col & 127;
        float v = acc[mi][ni][r] + bias[col];
        dst[((size_t)((b * 2 + h) * 2048 + n)) * 384 + e * 128 + kk] = f2b(v);
      }
}

// Masked scores, 64x128 tile, BK=128 (one barrier round per e-chunk).
// 1-D grid 4096: z = i&7 (XCD affinity), t=i>>3: y=t&31 (rows), x=t>>5 (cols).
// Output: fp16 scaled scores into sc16 (aliases abf), -60000 for masked.
__global__ __launch_bounds__(256) void k_scores(
    const bf16_t* __restrict__ qcat, const bf16_t* __restrict__ kcat,
    const int* __restrict__ adj, uint16_t* __restrict__ sc16) {
  __shared__ bf16_t lA[64 * 128];                // 16 KB
  __shared__ bf16_t lB[128 * 128];               // 32 KB
  int i = blockIdx.x;
  int z = i & 7, t = i >> 3;
  int y = t & 31, x = t >> 5;
  int h = z >> 2, b = z & 3;
  const bf16_t* A  = qcat + (size_t)(b * 2 + h) * 2048 * 384;
  const bf16_t* Bt = kcat + (size_t)(b * 2 + h) * 2048 * 384;
  const int* adjb = adj + (size_t)b * 2048 * 2048;
  int bm0 = y * 64, bn0 = x * 128;
  TILE_IDS64;

  uint32_t adjv[4][2];
#pragma unroll
  for (int mi = 0; mi < 4; ++mi)
#pragma unroll
    for (int ni = 0; ni < 2; ++ni) {
      int col = bn0 + wn + ni * 16 + l16;
      uint32_t v = 0;
#pragma unroll
      for (int r = 0; r < 4; ++r) {
        int row = bm0 + mi * 16 + quad * 4 + r;
        v |= ((uint32_t)adjb[(size_t)row * 2048 + col] & 3u) << (r * 8);
      }
      adjv[mi][ni] = v;
    }

  floatx4 sel[4][2];
  ZERO42(sel);
  for (int e = 0; e < 3; ++e) {
    __syncthreads();                             // protect prev round's reads
    stage128<64>(A + (size_t)bm0 * 384 + e * 128, 384, lA);
    stage128<128>(Bt + (size_t)bn0 * 384 + e * 128, 384, lB);
    __syncthreads();
    floatx4 acc[4][2];
    ZERO42(acc);
#pragma unroll
    for (int j = 0; j < 4; ++j) {
      bf16x8 af[4], bv[2];
#pragma unroll
      for (int mi = 0; mi < 4; ++mi) af[mi] = frag128(lA, mi * 16 + l16, j, quad);
#pragma unroll
      for (int ni = 0; ni < 2; ++ni) bv[ni] = frag128(lB, wn + ni * 16 + l16, j, quad);
#pragma unroll
      for (int mi = 0; mi < 4; ++mi)
#pragma unroll
        for (int ni = 0; ni < 2; ++ni)
          acc[mi][ni] = __builtin_amdgcn_mfma_f32_16x16x32_bf16(af[mi], bv[ni], acc[mi][ni], 0, 0, 0);
    }
#pragma unroll
    for (int mi = 0; mi < 4; ++mi)
#pragma unroll
      for (int ni = 0; ni < 2; ++ni) {
        uint32_t av = adjv[mi][ni];
#pragma unroll
        for (int r = 0; r < 4; ++r) {
          bool m = (((av >> (r * 8)) & 255u) == (uint32_t)(e + 1));
          sel[mi][ni][r] = m ? acc[mi][ni][r] : sel[mi][ni][r];
        }
      }
  }
  const float scale = 0.08838834764831845f;      // 1/sqrt(dk=128)
#pragma unroll
  for (int mi = 0; mi < 4; ++mi)
#pragma unroll
    for (int ni = 0; ni < 2; ++ni)
#pragma unroll
      for (int r = 0; r < 4; ++r) {
        int row = bm0 + mi * 16 + quad * 4 + r;
        int col = bn0 + wn + ni * 16 + l16;
        uint32_t a = (adjv[mi][ni] >> (r * 8)) & 255u;
        float v = (a == 0u) ? -60000.0f : sel[mi][ni][r] * scale;
        sc16[((size_t)z * 2048 + row) * 2048 + col] = f2h(v);
      }
}

// Row softmax: reads fp16 scores from sb, writes fp32 attn to `attn` and bf16
// attn IN-PLACE over sb (same addresses; full row in regs before stores).
__global__ __launch_bounds__(256) void k_softmax(uint16_t* sb, float* attn) {
  int row = blockIdx.x * 4 + (threadIdx.x >> 6);
  int lane = threadIdx.x & 63;
  uint16_t* p = sb + (size_t)row * 2048;
  float f[32];
  float mx = -3.4e38f;
#pragma unroll
  for (int j = 0; j < 4; ++j) {
    uint4 hv = ((const uint4*)p)[j * 64 + lane];
    const uint16_t* hu = (const uint16_t*)&hv;
#pragma unroll
    for (int q = 0; q < 8; ++q) {
      float v = h2f(hu[q]);
      f[j * 8 + q] = v;
      mx = fmaxf(mx, v);
    }
  }
#pragma unroll
  for (int off = 32; off; off >>= 1) mx = fmaxf(mx, __shfl_xor(mx, off));
  float s = 0.f;
#pragma unroll
  for (int k = 0; k < 32; ++k) { f[k] = __expf(f[k] - mx); s += f[k]; }
#pragma unroll
  for (int off = 32; off; off >>= 1) s += __shfl_xor(s, off);
  float inv = 1.0f / s;
  float* ar = attn + (size_t)row * 2048;
#pragma unroll
  for (int j = 0; j < 4; ++j) {
    float o[8];
#pragma unroll
    for (int q = 0; q < 8; ++q) o[q] = f[j * 8 + q] * inv;
    ((float4*)ar)[(j * 64 + lane) * 2 + 0] = *(float4*)&o[0];
    ((float4*)ar)[(j * 64 + lane) * 2 + 1] = *(float4*)&o[4];
    uint16_t ob[8];
#pragma unroll
    for (int q = 0; q < 8; ++q) ob[q] = f2b(o[q]);
    ((uint4*)p)[j * 64 + lane] = *(uint4*)ob;    // bf16 over the fp16 slot
  }
}

// h1 = A @ Wt with TRANSPOSED bf16 write: CT[slice][256][2048], slice = row>>11.
__global__ __launch_bounds__(256) void k_gemm_bf16T(
    const bf16_t* __restrict__ A, const bf16_t* __restrict__ Wt,
    bf16_t* __restrict__ CT) {
  __shared__ bf16_t lA[4096], lB[4096];
  int bm0 = blockIdx.y * 128, bn0 = blockIdx.x * 128;
  floatx4 acc[4][4];
  ZERO44(acc);
  gemm_core(A, 256, bm0, Wt, 256, bn0, 256, lA, lB, acc);
  TILE_IDS;
#pragma unroll
  for (int mi = 0; mi < 4; ++mi)
#pragma unroll
    for (int ni = 0; ni < 4; ++ni) {
      int row0 = bm0 + wm + mi * 16 + quad * 4;
      int col  = bn0 + wn + ni * 16 + l16;
      int s = row0 >> 11, n = row0 & 2047;
      u16x4 v = { f2b(acc[mi][ni][0]), f2b(acc[mi][ni][1]),
                  f2b(acc[mi][ni][2]), f2b(acc[mi][ni][3]) };
      *(u16x4*)&CT[(size_t)s * 524288 + (size_t)col * 2048 + n] = v;
    }
}

// sum_nei = attn @ h1, 64x128 tile, BK=64, z->XCD swizzle.
// Epilogue: x_new = x_old + relu(acc + gcn_b).
__global__ __launch_bounds__(256) void k_spmm(
    const bf16_t* __restrict__ abf, const bf16_t* __restrict__ h1T,
    long sBb, long sBh, const float* __restrict__ bias,
    const float* __restrict__ rin, long rib, long rih,
    float* __restrict__ rout,
    bf16_t* __restrict__ obf, long obb, long obh, int ldo) {
  __shared__ bf16_t lA[64 * 64];                 // 8 KB
  __shared__ bf16_t lB[128 * 64];                // 16 KB
  int i = blockIdx.x;
  int z = i & 7, t = i >> 3;
  int x = t & 1, y = t >> 1;
  int h = z >> 2, b = z & 3;
  const bf16_t* A  = abf + (size_t)z * 2048 * 2048;
  const bf16_t* Bt = h1T + (size_t)b * sBb + (size_t)h * sBh;
  const float* rz  = rin + (size_t)b * rib + (size_t)h * rih;
  bf16_t* oz = obf + (size_t)b * obb + (size_t)h * obh;
  int bm0 = y * 64, bn0 = x * 128;
  TILE_IDS64;
  floatx4 acc[4][2];
  ZERO42(acc);
  for (int k0 = 0; k0 < 2048; k0 += 64) {
    __syncthreads();
    stage64<64>(A + (size_t)bm0 * 2048 + k0, 2048, lA);
    stage64<128>(Bt + (size_t)bn0 * 2048 + k0, 2048, lB);
    __syncthreads();
#pragma unroll
    for (int j = 0; j < 2; ++j) {
      bf16x8 af[4], bv[2];
#pragma unroll
      for (int mi = 0; mi < 4; ++mi) af[mi] = frag64(lA, mi * 16 + l16, j, quad);
#pragma unroll
      for (int ni = 0; ni < 2; ++ni) bv[ni] = frag64(lB, wn + ni * 16 + l16, j, quad);
#pragma unroll
      for (int mi = 0; mi < 4; ++mi)
#pragma unroll
        for (int ni = 0; ni < 2; ++ni)
          acc[mi][ni] = __builtin_amdgcn_mfma_f32_16x16x32_bf16(af[mi], bv[ni], acc[mi][ni], 0, 0, 0);
    }
  }
#pragma unroll
  for (int mi = 0; mi < 4; ++mi)
#pragma unroll
    for (int ni = 0; ni < 2; ++ni)
#pragma unroll
      for (int r = 0; r < 4; ++r) {
        int row = bm0 + mi * 16 + quad * 4 + r;
        int col = bn0 + wn + ni * 16 + l16;
        float s = acc[mi][ni][r] + bias[col];
        float xn = rz[(size_t)row * 256 + col] + fmaxf(s, 0.f);
        if (rout) rout[((size_t)z * 2048 + row) * 256 + col] = xn;
        oz[(size_t)row * ldo + col] = f2b(xn);
      }
}

// Final: out = xcat(8192x512) @ aggW(512x256) + agg_b, fp32.
__global__ __launch_bounds__(256) void k_final(
    const bf16_t* __restrict__ xcat, const bf16_t* __restrict__ aWT,
    const float* __restrict__ ab, float* __restrict__ out) {
  __shared__ bf16_t lA[4096], lB[4096];
  int bm0 = blockIdx.y * 128, bn0 = blockIdx.x * 128;
  floatx4 acc[4][4];
  ZERO44(acc);
  gemm_core(xcat, 512, bm0, aWT, 512, bn0, 512, lA, lB, acc);
  TILE_IDS;
#pragma unroll
  for (int mi = 0; mi < 4; ++mi)
#pragma unroll
    for (int ni = 0; ni < 4; ++ni)
#pragma unroll
      for (int r = 0; r < 4; ++r) {
        int row = bm0 + wm + mi * 16 + quad * 4 + r;
        int col = bn0 + wn + ni * 16 + l16;
        out[(size_t)row * 256 + col] = acc[mi][ni][r] + ab[col];
      }
}

// ---------------------------------------------------------------------------
extern "C" void kernel_launch(void* const* d_in, const int* in_sizes, int n_in,
                              void* d_out, int out_size, void* d_ws, size_t ws_size,
                              hipStream_t stream) {
  const float* x   = (const float*)d_in[0];
  const int*   adj = (const int*)d_in[1];
  const float* Wq  = (const float*)d_in[2];
  const float* bq  = (const float*)d_in[3];
  const float* Wk  = (const float*)d_in[4];
  const float* bk  = (const float*)d_in[5];
  const float* gW  = (const float*)d_in[6];
  const float* gb  = (const float*)d_in[7];
  const float* aW  = (const float*)d_in[8];
  const float* ab  = (const float*)d_in[9];
  float* out = (float*)d_out;                    // (4,2048,256)
  float* sc  = out + 2097152;                    // graph_attention (2,4,2048,2048)

  char* w = (char*)d_ws;
  bf16_t* xb   = (bf16_t*)w; w += 4194304;       // 8192x256 bf16
  bf16_t* WqkT = (bf16_t*)w; w += 786432;        // 6x256x256
  bf16_t* gWT  = (bf16_t*)w; w += 262144;        // 2x256x256
  bf16_t* aWT  = (bf16_t*)w; w += 262144;        // 256x512
  bf16_t* qcat = (bf16_t*)w; w += 12582912;      // [b][h][2048][384]
  bf16_t* kcat = (bf16_t*)w; w += 12582912;
  bf16_t* abf  = (bf16_t*)w; w += 67108864;      // [h][b][2048][2048]: fp16 scores then bf16 attn
  bf16_t* h1T  = (bf16_t*)w; w += 4194304;       // [b][256][2048]
  float*  x1   = (float*)w;  w += 16777216;      // [h][b][2048][256] fp32
  bf16_t* x1b  = (bf16_t*)w; w += 8388608;       // [h][b][2048][256] bf16
  bf16_t* h1T1 = qcat;                           // alias (free after k_scores)
  bf16_t* xcat = kcat;                           // alias (free after k_scores)

  k_cast_x<<<1024, 256, 0, stream>>>(x, xb);
  k_cast_w<<<2560, 256, 0, stream>>>(Wq, Wk, gW, aW, WqkT, gWT, aWT);
  k_gemm_proj<<<dim3(2, 64, 6), 256, 0, stream>>>(xb, WqkT, bq, bk, qcat, kcat);
  k_scores<<<4096, 256, 0, stream>>>(qcat, kcat, adj, (uint16_t*)abf);
  k_softmax<<<4096, 256, 0, stream>>>((uint16_t*)abf, sc);
  // GCN iter 0 (h1 shared across heads since x0 identical); transposed write
  k_gemm_bf16T<<<dim3(2, 64, 1), 256, 0, stream>>>(xb, gWT, h1T);
  k_spmm<<<512, 256, 0, stream>>>(abf, h1T, 524288L, 0L, gb,
                                  x, 524288L, 0L, x1,
                                  x1b, 524288L, 2097152L, 256);
  // GCN iter 1 (per-head x)
  k_gemm_bf16T<<<dim3(2, 128, 1), 256, 0, stream>>>(x1b, gWT + 65536, h1T1);
  k_spmm<<<512, 256, 0, stream>>>(abf, h1T1, 524288L, 2097152L, gb + 256,
                                  x1, 524288L, 2097152L, nullptr,
                                  xcat, 1048576L, 256L, 512);
  // Final aggregation
  k_final<<<dim3(2, 64, 1), 256, 0, stream>>>(xcat, aWT, ab, out);
}